// Round 4
// baseline (24.733 us; speedup 1.0000x reference)
//
#include <hip/hip_runtime.h>
#include <cmath>

#define E_EXPERTS 16
#define D_DIM 2048
#define H_DIM 2048

// ws layout: ws[0..15] = logits, ws[16..] = h[2][H_DIM]

// ---------------------------------------------------------------------------
// K0: logits[e] = dot(Wg[e], x) + bg[e]. 16 blocks (one expert each) x 256
// threads. 131 KB of Wg read across 16 CUs in parallel -> ~1-2 us.
// ---------------------------------------------------------------------------
__global__ __launch_bounds__(256) void gate_logits(
    const float* __restrict__ Wg, const float* __restrict__ bg,
    const float* __restrict__ x, float* __restrict__ logits) {
    const int tid  = threadIdx.x;
    const int wave = tid >> 6;
    const int lane = tid & 63;
    const int e    = blockIdx.x;

    __shared__ float sred[4];

    const float4* wrow = (const float4*)(Wg + (size_t)e * D_DIM);
    const float4* xv   = (const float4*)x;
    float acc = 0.f;
#pragma unroll
    for (int i = 0; i < 2; ++i) {          // 512 float4 over 256 threads
        float4 w  = wrow[tid + i * 256];
        float4 xx = xv[tid + i * 256];
        acc += w.x * xx.x + w.y * xx.y + w.z * xx.z + w.w * xx.w;
    }
#pragma unroll
    for (int off = 32; off; off >>= 1) acc += __shfl_down(acc, off, 64);
    if (lane == 0) sred[wave] = acc;
    __syncthreads();
    if (tid == 0) logits[e] = sred[0] + sred[1] + sred[2] + sred[3] + bg[e];
}

// Every thread derives top-2 + normalized gates from logits[16] (64 B read,
// ~60 VALU cycles, identical in every block -> deterministic).
__device__ __forceinline__ void top2_from_logits(
    const float* __restrict__ logits, int& i0, int& i1, float& tk0, float& tk1) {
    float l[E_EXPERTS];
#pragma unroll
    for (int e = 0; e < E_EXPERTS; ++e) l[e] = logits[e];
    float m = -1e30f;
#pragma unroll
    for (int e = 0; e < E_EXPERTS; ++e) m = fmaxf(m, l[e]);
    float p[E_EXPERTS];
    float s = 0.f;
#pragma unroll
    for (int e = 0; e < E_EXPERTS; ++e) { p[e] = __expf(l[e] - m); s += p[e]; }
    i0 = 0; float v0 = p[0];
#pragma unroll
    for (int e = 1; e < E_EXPERTS; ++e) if (p[e] > v0) { v0 = p[e]; i0 = e; }
    i1 = -1; float v1 = -1.f;
#pragma unroll
    for (int e = 0; e < E_EXPERTS; ++e) {
        if (e == i0) continue;
        if (p[e] > v1) { v1 = p[e]; i1 = e; }
    }
    float g0 = v0 / s, g1 = v1 / s;
    float denom = g0 + g1 + 1e-6f;
    tk0 = g0 / denom;
    tk1 = g1 / denom;
}

// ---------------------------------------------------------------------------
// K1: h[k][r] = tanh(W1[e_k][r].x + b1[e_k][r]). 1024 blocks x 256 threads,
// one wave per (k,r). Coalesced 1KB/instr float4 row loads.
// ---------------------------------------------------------------------------
__global__ __launch_bounds__(256) void moe_h(
    const float* __restrict__ x,  const float* __restrict__ W1,
    const float* __restrict__ b1, float* __restrict__ ws) {
    const float* logits = ws;
    float* h = ws + 16;

    const int tid  = threadIdx.x;
    const int wave = tid >> 6;
    const int lane = tid & 63;

    // x fragment first so the loads overlap the logits read + top-2 VALU.
    const float4* xv = (const float4*)x;
    float4 xx[8];
#pragma unroll
    for (int i = 0; i < 8; ++i) xx[i] = xv[lane + i * 64];

    int i0, i1; float tk0, tk1;
    top2_from_logits(logits, i0, i1, tk0, tk1);

    const int gw = blockIdx.x * 4 + wave;   // 0..4095
    const int k  = gw >> 11;
    const int r  = gw & (H_DIM - 1);
    const int e  = (k == 0) ? i0 : i1;

    const float4* wrow = (const float4*)(W1 + ((size_t)e * H_DIM + r) * D_DIM);
    float acc = 0.f;
#pragma unroll
    for (int i = 0; i < 8; ++i) {
        float4 w = wrow[lane + i * 64];
        acc += w.x * xx[i].x + w.y * xx[i].y + w.z * xx[i].z + w.w * xx[i].w;
    }
#pragma unroll
    for (int off = 32; off; off >>= 1) acc += __shfl_down(acc, off, 64);
    if (lane == 0) h[k * H_DIM + r] = tanhf(acc + b1[(size_t)e * H_DIM + r]);
}

// ---------------------------------------------------------------------------
// K2: out[o] = sum_k tkg[k]*(W2[e_k][o].h[k] + b2[e_k][o]).
// 1024 blocks x 256 threads, one wave per (o,k); LDS combine.
// ---------------------------------------------------------------------------
__global__ __launch_bounds__(256) void moe_out(
    const float* __restrict__ W2, const float* __restrict__ b2,
    const float* __restrict__ ws, float* __restrict__ out) {
    const float* logits = ws;
    const float* h = ws + 16;

    const int tid  = threadIdx.x;
    const int wave = tid >> 6;
    const int lane = tid & 63;

    int i0, i1; float tk0, tk1;
    top2_from_logits(logits, i0, i1, tk0, tk1);

    const int o = blockIdx.x * 2 + (wave & 1);  // 0..2047
    const int k = wave >> 1;                     // 0/1
    const int e = (k == 0) ? i0 : i1;

    __shared__ float sred[4];

    const float4* wrow = (const float4*)(W2 + ((size_t)e * H_DIM + o) * H_DIM);
    const float4* hv   = (const float4*)(h + k * H_DIM);
    float acc = 0.f;
#pragma unroll
    for (int i = 0; i < 8; ++i) {
        float4 w  = wrow[lane + i * 64];
        float4 hh = hv[lane + i * 64];
        acc += w.x * hh.x + w.y * hh.y + w.z * hh.z + w.w * hh.w;
    }
#pragma unroll
    for (int off = 32; off; off >>= 1) acc += __shfl_down(acc, off, 64);
    if (lane == 0) sred[wave] = acc;
    __syncthreads();

    if (tid < 2) {
        const int oo = blockIdx.x * 2 + tid;
        float eo0 = sred[tid]     + b2[(size_t)i0 * H_DIM + oo];
        float eo1 = sred[2 + tid] + b2[(size_t)i1 * H_DIM + oo];
        out[oo] = tk0 * eo0 + tk1 * eo1;
    }
}

extern "C" void kernel_launch(void* const* d_in, const int* in_sizes, int n_in,
                              void* d_out, int out_size, void* d_ws, size_t ws_size,
                              hipStream_t stream) {
    const float* x  = (const float*)d_in[0];
    const float* Wg = (const float*)d_in[1];
    const float* bg = (const float*)d_in[2];
    const float* W1 = (const float*)d_in[3];
    const float* b1 = (const float*)d_in[4];
    const float* W2 = (const float*)d_in[5];
    const float* b2 = (const float*)d_in[6];
    float* out  = (float*)d_out;
    float* ws_f = (float*)d_ws;

    gate_logits<<<16, 256, 0, stream>>>(Wg, bg, x, ws_f);
    moe_h<<<1024, 256, 0, stream>>>(x, W1, b1, ws_f);
    moe_out<<<1024, 256, 0, stream>>>(W2, b2, ws_f, out);
}